// Round 9
// baseline (97.474 us; speedup 1.0000x reference)
//
#include <hip/hip_runtime.h>
#include <hip/hip_fp16.h>

// Problem constants (B, L, C, H, W) = (2, 48, 8, 48, 48)
constexpr int B = 2, L = 48, C = 8, H = 48, W = 48;
constexpr int HW = H * W;   // 2304

constexpr int TPB    = 256;        // threads per block (= pixels per chunk)
constexpr int CHUNKS = HW / TPB;   // 9
constexpr int NOCT   = 6;          // oct groups g=0..5 (8 t's each)
constexpr int NSLOT  = 24;         // max parity k-slots per block

// LDS: one fp16 frame (36,864 B) + cum stage [24][256][2] f32 (49,152 B)
constexpr int FRAME_BYTES = HW * C * 2;                 // 36,864
constexpr int CUMS_BYTES  = NSLOT * TPB * 2 * 4;        // 49,152
constexpr int SMEM_BYTES  = FRAME_BYTES + CUMS_BYTES;   // 86,016 (epilogue reuses 64 KB)

constexpr int NCUM        = B * 2 * HW;               // 9216 cumsum threads
constexpr int CUM_BLOCKS  = NCUM / 256;               // 36
constexpr int NCONV       = B * L * HW;               // 221184 convert threads
constexpr int CONV_BLOCKS = (NCONV + 255) / 256;      // 864

// ---------------------------------------------------------------------------
// Prep kernel (unchanged): cumsum of flows -> cum2 (B,L,HW,2) fp32 (same
// accumulation order as jnp.cumsum); images -> fp16 channel-last imgH.
// ---------------------------------------------------------------------------
__global__ void prep_kernel(const float* __restrict__ flows,
                            const float* __restrict__ images,
                            float* __restrict__ cum2,
                            __half* __restrict__ imgH) {
    if (blockIdx.x < CUM_BLOCKS) {
        int tid  = blockIdx.x * 256 + threadIdx.x;     // < NCUM
        int pix  = tid % HW;
        int comp = (tid / HW) & 1;
        int b    = tid / (2 * HW);
        const float* src = flows + (size_t)b * L * 2 * HW + (size_t)comp * HW + pix;
        float*       dst = cum2  + ((size_t)b * L * HW + pix) * 2 + comp;
        float acc = 0.0f;
#pragma unroll
        for (int l = 0; l < L; ++l) {
            acc += src[(size_t)l * 2 * HW];
            dst[(size_t)l * HW * 2] = acc;
        }
    } else {
        int tid = (blockIdx.x - CUM_BLOCKS) * 256 + threadIdx.x;
        if (tid >= NCONV) return;
        int pix = tid % HW;
        int bl  = tid / HW;
        const float* src = images + (size_t)bl * C * HW + pix;
        __half h[C];
#pragma unroll
        for (int c = 0; c < C; ++c) h[c] = __float2half(src[(size_t)c * HW]);
        float4* dst = reinterpret_cast<float4*>(imgH + ((size_t)bl * HW + pix) * C);
        *dst = *reinterpret_cast<float4*>(h);
    }
}

// ---------------------------------------------------------------------------
// Per-sample coordinate math (exact wrap ladder, matches jnp.remainder for
// |v| < 8; tap validity on UNCLAMPED floored coords, matching the reference).
// ---------------------------------------------------------------------------
struct SampleGeom {
    float w00, w10, w01, w11;
    int x0, y0;     // unclamped floor corner; y0 is UNBOUNDED (y not wrapped)
};

__device__ __forceinline__ SampleGeom sample_geom(float base_gx_p1, float base_gy,
                                                  float relx, float rely) {
    float v = base_gx_p1 + relx;
    v = (v >= 2.0f) ? v - 2.0f : v;
    v = (v >= 2.0f) ? v - 2.0f : v;
    v = (v >= 2.0f) ? v - 2.0f : v;
    v = (v <  0.0f) ? v + 2.0f : v;
    v = (v <  0.0f) ? v + 2.0f : v;
    v = (v <  0.0f) ? v + 2.0f : v;

    float ix = (v * (float)W - 1.0f) * 0.5f;              // [-0.5, 47.5)
    float gy = base_gy + rely;
    float iy = ((gy + 1.0f) * (float)H - 1.0f) * 0.5f;

    float x0f = floorf(ix), y0f = floorf(iy);
    float wx1 = ix - x0f,   wy1 = iy - y0f;
    float wx0 = 1.0f - wx1, wy0 = 1.0f - wy1;

    float vx0 = (x0f >= 0.0f  && x0f <= (float)(W - 1)) ? 1.0f : 0.0f;
    float vx1 = (x0f >= -1.0f && x0f <= (float)(W - 2)) ? 1.0f : 0.0f;
    float vy0 = (y0f >= 0.0f  && y0f <= (float)(H - 1)) ? 1.0f : 0.0f;
    float vy1 = (y0f >= -1.0f && y0f <= (float)(H - 2)) ? 1.0f : 0.0f;

    SampleGeom g;
    g.w00 = wx0 * wy0 * vx0 * vy0;
    g.w10 = wx1 * wy0 * vx1 * vy0;
    g.w01 = wx0 * wy1 * vx0 * vy1;
    g.w11 = wx1 * wy1 * vx1 * vy1;
    g.x0  = (int)x0f;
    g.y0  = (int)y0f;
    return g;
}

// ---------------------------------------------------------------------------
// Register-staged frame: 9 x global_load_dwordx4 per thread (T14 issue-early),
// written to LDS after a barrier (write-late). Static indices (rule #20).
// ---------------------------------------------------------------------------
__device__ __forceinline__ void load_frame_regs(const __half* __restrict__ gsrc,
                                                int tid, float4 fr[9]) {
#pragma unroll
    for (int i = 0; i < 9; ++i)
        fr[i] = *reinterpret_cast<const float4*>(gsrc + (size_t)(i * TPB + tid) * C);
}

__device__ __forceinline__ void write_frame_lds(__half* frame, int tid, const float4 fr[9]) {
#pragma unroll
    for (int i = 0; i < 9; ++i)
        *reinterpret_cast<float4*>(frame + (size_t)(i * TPB + tid) * C) = fr[i];
}

// ---------------------------------------------------------------------------
// Gather 4 taps from the LDS frame and accumulate 8 channels.
// Double-sided clamps (y0 unbounded); zero validity weights neutralize
// clamped taps (0 * finite LDS data — no NaN possible).
// ---------------------------------------------------------------------------
__device__ __forceinline__ void gather_mix(const __half* fb, const SampleGeom& g,
                                           float acc[C]) {
    int x0 = min(max(g.x0,     0), W - 1);
    int x1 = min(max(g.x0 + 1, 0), W - 1);
    int y0 = min(max(g.y0,     0), H - 1);
    int y1 = min(max(g.y0 + 1, 0), H - 1);
    float4 r00 = *reinterpret_cast<const float4*>(fb + (y0 * W + x0) * C);
    float4 r10 = *reinterpret_cast<const float4*>(fb + (y0 * W + x1) * C);
    float4 r01 = *reinterpret_cast<const float4*>(fb + (y1 * W + x0) * C);
    float4 r11 = *reinterpret_cast<const float4*>(fb + (y1 * W + x1) * C);
    auto mix = [&](const float4& raw, float wgt) {
        const __half2* hc = reinterpret_cast<const __half2*>(&raw);
#pragma unroll
        for (int c = 0; c < 4; ++c) {
            float2 f = __half22float2(hc[c]);
            acc[2 * c]     += wgt * f.x;
            acc[2 * c + 1] += wgt * f.y;
        }
    };
    mix(r00, g.w00); mix(r10, g.w10); mix(r01, g.w01); mix(r11, g.w11);
}

// ---------------------------------------------------------------------------
// Main kernel: oct-t LDS-gather pscan, k split by parity, T14 reg-staging.
// Block = (chunk, oct g, {parity, b}); 256 threads, 1 pixel each.
// t-set = {g, 11-g, 12+g, 23-g, 24+g, 35-g, 36+g, 47-g}; k = par, par+2, ...
// <= 47-g (196 samples/pixel per (chunk,b) pair of parity blocks, uniform).
//
// Pipeline per iteration (fixes R8's per-iteration vmcnt(0) staging drain):
//   gather(k) from LDS            <- loads for frame k+2 in flight underneath
//   __syncthreads                 <- drains those loads (they had ~1+ gather
//                                    phase to complete) + gathers done
//   ds_write regs -> LDS (k+2)
//   __syncthreads                 <- frame k+2 visible
//   issue global loads (k+4) -> regs   <- spans the NEXT gather phase
//
// cum for all 24 parity k-slots staged in LDS up front (ds_read per iter
// instead of a dependent global load at each iteration top).
// grid = (9, 6, 4) = 216 blocks; LDS 86 KB (1 block/CU).
// Parity 0 writes `out`, parity 1 writes `podd`; reduce_kernel sums.
// ---------------------------------------------------------------------------
__global__ __launch_bounds__(256) void scan_oct2_kernel(const float* __restrict__ cum2,
                                                        const __half* __restrict__ imgH,
                                                        float* __restrict__ out,
                                                        float* __restrict__ podd) {
    const int tid  = threadIdx.x;
    const int pix0 = blockIdx.x * TPB;
    const int pix  = pix0 + tid;
    const int g    = blockIdx.y;
    const int par  = blockIdx.z & 1;
    const int b    = blockIdx.z >> 1;

    int tj[8];
#pragma unroll
    for (int j = 0; j < 4; ++j) {
        tj[2 * j]     = 12 * j + g;
        tj[2 * j + 1] = 12 * j + 11 - g;
    }
    const int kmax = 47 - g;

    const int w = pix % W;
    const int h = pix / W;
    const float base_gx_p1 = (2 * w + 1) * (1.0f / W);
    const float base_gy    = (2 * h + 1) * (1.0f / H) - 1.0f;

    __shared__ __align__(16) unsigned char smem[SMEM_BYTES];
    __half* frame = reinterpret_cast<__half*>(smem);                    // 36,864 B
    float*  cumS  = reinterpret_cast<float*>(smem + FRAME_BYTES);       // [24][256][2]

    const float* cb = cum2 + ((size_t)b * L * HW + pix) * 2;

    float ctx[8], cty[8];
#pragma unroll
    for (int j = 0; j < 8; ++j) {
        float2 c = *reinterpret_cast<const float2*>(cb + (size_t)tj[j] * HW * 2);
        ctx[j] = c.x; cty[j] = c.y;
    }

    // stage cum for all 24 parity slots (k = par + 2*slot <= 47 always valid)
#pragma unroll
    for (int slot = 0; slot < NSLOT; ++slot) {
        float2 v = *reinterpret_cast<const float2*>(cb + (size_t)(par + 2 * slot) * HW * 2);
        *reinterpret_cast<float2*>(cumS + (slot * TPB + tid) * 2) = v;
    }

    float acc[8][C];
#pragma unroll
    for (int j = 0; j < 8; ++j)
#pragma unroll
        for (int c = 0; c < C; ++c) acc[j][c] = 0.0f;

    const __half* gb = imgH + (size_t)b * L * HW * C;

    // ---- prologue: frame k0 into LDS; loads for k0+2 left in flight ----
    float4 fr[9];
    load_frame_regs(gb + (size_t)par * HW * C, tid, fr);
    __syncthreads();                              // cumS visible, fr(k0) complete
    write_frame_lds(frame, tid, fr);
    __syncthreads();                              // frame k0 visible
    if (par + 2 <= kmax)
        load_frame_regs(gb + (size_t)(par + 2) * HW * C, tid, fr);

    for (int k = par; k <= kmax; k += 2) {
        const int slot = (k - par) >> 1;
        const float2 ck = *reinterpret_cast<const float2*>(cumS + (slot * TPB + tid) * 2);

#pragma unroll
        for (int j = 0; j < 8; ++j) {
            if (tj[j] >= k) {   // block-uniform guard
                SampleGeom gm = sample_geom(base_gx_p1, base_gy,
                                            ctx[j] - ck.x, cty[j] - ck.y);
                gather_mix(frame, gm, acc[j]);
            }
        }

        __syncthreads();        // gathers done; fr(k+2) loads drained (in flight
                                // during the whole gather phase above)
        if (k + 2 <= kmax)
            write_frame_lds(frame, tid, fr);
        __syncthreads();        // frame k+2 visible
        if (k + 4 <= kmax)
            load_frame_regs(gb + (size_t)(k + 4) * HW * C, tid, fr);  // spans next gather
    }

    // ---- epilogue: transpose acc through LDS for coalesced stores ----
    // (all waves past the final barrier; smem is free to reuse — 64 KB needed)
    float* accT = reinterpret_cast<float*>(smem);       // [64][256]
#pragma unroll
    for (int j = 0; j < 8; ++j)
#pragma unroll
        for (int c = 0; c < C; ++c)
            accT[(j * 8 + c) * TPB + tid] = acc[j][c];
    __syncthreads();

    float* dst = par ? podd : out;
    const int lane = tid & 63;
    const int wv   = tid >> 6;
#pragma unroll
    for (int r = 0; r < 16; ++r) {
        int pl = wv + 4 * r;            // plane 0..63 = (j, c)
        int j  = pl >> 3, c = pl & 7;
        float4 v = *reinterpret_cast<float4*>(&accT[pl * TPB + lane * 4]);
        *reinterpret_cast<float4*>(dst + ((size_t)(b * L + tj[j]) * C + c) * HW
                                   + pix0 + lane * 4) = v;
    }
}

// ---------------------------------------------------------------------------
// Reduce: out += podd (float4). Fixed order -> bitwise deterministic.
// ---------------------------------------------------------------------------
__global__ void reduce_kernel(float* __restrict__ out, const float* __restrict__ podd) {
    int i = blockIdx.x * blockDim.x + threadIdx.x;
    constexpr int N4 = B * L * C * HW / 4;   // 442,368 float4s
    if (i < N4) {
        float4 a = reinterpret_cast<float4*>(out)[i];
        float4 p = reinterpret_cast<const float4*>(podd)[i];
        a.x += p.x; a.y += p.y; a.z += p.z; a.w += p.w;
        reinterpret_cast<float4*>(out)[i] = a;
    }
}

// ---------------------------------------------------------------------------
extern "C" void kernel_launch(void* const* d_in, const int* in_sizes, int n_in,
                              void* d_out, int out_size, void* d_ws, size_t ws_size,
                              hipStream_t stream) {
    const float* flows  = (const float*)d_in[0];   // (B, L, 2, H, W) fp32
    const float* images = (const float*)d_in[1];   // (B, L, C, H, W) fp32
    float* out = (float*)d_out;                    // (B, L, C, H, W) fp32

    const size_t cum_elems  = (size_t)B * L * 2 * HW;     // 442,368 f32 (1.77 MB)
    const size_t imgH_elems = (size_t)B * L * HW * C;     // fp16 (7.08 MB)

    float*  cum2 = (float*)d_ws;
    __half* imgH = (__half*)(cum2 + cum_elems);
    float*  podd = (float*)(imgH + imgH_elems);           // 7.08 MB (parity-1 partial)
    // total ws use: 1.77 + 7.08 + 7.08 = 15.93 MB (<= 16.5 MB proven in R4)

    prep_kernel<<<CUM_BLOCKS + CONV_BLOCKS, 256, 0, stream>>>(flows, images, cum2, imgH);

    dim3 grid(CHUNKS, NOCT, 4);                           // (9, 6, 2b x 2parity) = 216
    scan_oct2_kernel<<<grid, 256, 0, stream>>>(cum2, imgH, out, podd);

    constexpr int N4 = B * L * C * HW / 4;                // 442,368 float4s
    reduce_kernel<<<(N4 + 255) / 256, 256, 0, stream>>>(out, podd);
}

// Round 10
// 51.838 us; speedup vs baseline: 1.8804x; 1.8804x over previous
//
#include <hip/hip_runtime.h>
#include <hip/hip_fp16.h>

// Problem constants (B, L, C, H, W) = (2, 48, 8, 48, 48)
constexpr int B = 2, L = 48, C = 8, H = 48, W = 48;
constexpr int HW = H * W;   // 2304

constexpr int TPB    = 256;        // threads per block (= pixels per chunk)
constexpr int CHUNKS = HW / TPB;   // 9
constexpr int NOCT   = 6;          // oct groups g=0..5 (8 t's each)

constexpr int OUT_ELEMS = B * L * C * HW;             // 1,769,472 floats (7.08 MB)

constexpr int NCUM        = B * 2 * HW;               // 9216 cumsum threads
constexpr int CUM_BLOCKS  = NCUM / 256;               // 36
constexpr int NCONV       = B * L * HW;               // 221184 convert threads
constexpr int CONV_BLOCKS = (NCONV + 255) / 256;      // 864

// ---------------------------------------------------------------------------
// Prep kernel (unchanged): cumsum of flows -> cum2 (B,L,HW,2) fp32 (same
// accumulation order as jnp.cumsum); images -> fp16 channel-last imgH.
// ---------------------------------------------------------------------------
__global__ void prep_kernel(const float* __restrict__ flows,
                            const float* __restrict__ images,
                            float* __restrict__ cum2,
                            __half* __restrict__ imgH) {
    if (blockIdx.x < CUM_BLOCKS) {
        int tid  = blockIdx.x * 256 + threadIdx.x;     // < NCUM
        int pix  = tid % HW;
        int comp = (tid / HW) & 1;
        int b    = tid / (2 * HW);
        const float* src = flows + (size_t)b * L * 2 * HW + (size_t)comp * HW + pix;
        float*       dst = cum2  + ((size_t)b * L * HW + pix) * 2 + comp;
        float acc = 0.0f;
#pragma unroll
        for (int l = 0; l < L; ++l) {
            acc += src[(size_t)l * 2 * HW];
            dst[(size_t)l * HW * 2] = acc;
        }
    } else {
        int tid = (blockIdx.x - CUM_BLOCKS) * 256 + threadIdx.x;
        if (tid >= NCONV) return;
        int pix = tid % HW;
        int bl  = tid / HW;
        const float* src = images + (size_t)bl * C * HW + pix;
        __half h[C];
#pragma unroll
        for (int c = 0; c < C; ++c) h[c] = __float2half(src[(size_t)c * HW]);
        float4* dst = reinterpret_cast<float4*>(imgH + ((size_t)bl * HW + pix) * C);
        *dst = *reinterpret_cast<float4*>(h);
    }
}

// ---------------------------------------------------------------------------
// Per-sample coordinate math (exact wrap ladder, matches jnp.remainder for
// |v| < 8; tap validity on UNCLAMPED floored coords, matching the reference).
// ---------------------------------------------------------------------------
struct SampleGeom {
    float w00, w10, w01, w11;
    int x0, y0;     // unclamped floor corner; y0 is UNBOUNDED (y not wrapped)
};

__device__ __forceinline__ SampleGeom sample_geom(float base_gx_p1, float base_gy,
                                                  float relx, float rely) {
    float v = base_gx_p1 + relx;
    v = (v >= 2.0f) ? v - 2.0f : v;
    v = (v >= 2.0f) ? v - 2.0f : v;
    v = (v >= 2.0f) ? v - 2.0f : v;
    v = (v <  0.0f) ? v + 2.0f : v;
    v = (v <  0.0f) ? v + 2.0f : v;
    v = (v <  0.0f) ? v + 2.0f : v;

    float ix = (v * (float)W - 1.0f) * 0.5f;              // [-0.5, 47.5)
    float gy = base_gy + rely;
    float iy = ((gy + 1.0f) * (float)H - 1.0f) * 0.5f;

    float x0f = floorf(ix), y0f = floorf(iy);
    float wx1 = ix - x0f,   wy1 = iy - y0f;
    float wx0 = 1.0f - wx1, wy0 = 1.0f - wy1;

    float vx0 = (x0f >= 0.0f  && x0f <= (float)(W - 1)) ? 1.0f : 0.0f;
    float vx1 = (x0f >= -1.0f && x0f <= (float)(W - 2)) ? 1.0f : 0.0f;
    float vy0 = (y0f >= 0.0f  && y0f <= (float)(H - 1)) ? 1.0f : 0.0f;
    float vy1 = (y0f >= -1.0f && y0f <= (float)(H - 2)) ? 1.0f : 0.0f;

    SampleGeom g;
    g.w00 = wx0 * wy0 * vx0 * vy0;
    g.w10 = wx1 * wy0 * vx1 * vy0;
    g.w01 = wx0 * wy1 * vx0 * vy1;
    g.w11 = wx1 * wy1 * vx1 * vy1;
    g.x0  = (int)x0f;
    g.y0  = (int)y0f;
    return g;
}

// ---------------------------------------------------------------------------
// Stage one fp16 frame (2304 records x 16B = 36.9 KB) global -> LDS, linear.
// 256 threads x 9 records; wave-uniform base + lane*16 (global_load_lds req).
// ---------------------------------------------------------------------------
#if defined(__has_builtin)
#if __has_builtin(__builtin_amdgcn_global_load_lds)
#define HAVE_GLD_LDS 1
#endif
#endif

__device__ __forceinline__ void stage_frame(const __half* __restrict__ gsrc,
                                            __half* lds_base, int tid) {
#ifdef HAVE_GLD_LDS
#pragma unroll
    for (int i = 0; i < 9; ++i) {
        const int r = i * 256 + tid;
        __builtin_amdgcn_global_load_lds(
            (const __attribute__((address_space(1))) void*)(gsrc + (size_t)r * C),
            (__attribute__((address_space(3))) void*)(lds_base + (size_t)r * C),
            16, 0, 0);
    }
#else
#pragma unroll
    for (int i = 0; i < 9; ++i) {
        const int r = i * 256 + tid;
        float4 v = *reinterpret_cast<const float4*>(gsrc + (size_t)r * C);
        *reinterpret_cast<float4*>(lds_base + (size_t)r * C) = v;
    }
#endif
}

// ---------------------------------------------------------------------------
// Gather 4 taps from the LDS frame and accumulate 8 channels.
// Double-sided clamps (y0 unbounded); zero validity weights neutralize
// clamped taps (0 * finite LDS data — no NaN possible).
// ---------------------------------------------------------------------------
__device__ __forceinline__ void gather_mix(const __half* fb, const SampleGeom& g,
                                           float acc[C]) {
    int x0 = min(max(g.x0,     0), W - 1);
    int x1 = min(max(g.x0 + 1, 0), W - 1);
    int y0 = min(max(g.y0,     0), H - 1);
    int y1 = min(max(g.y0 + 1, 0), H - 1);
    float4 r00 = *reinterpret_cast<const float4*>(fb + (y0 * W + x0) * C);
    float4 r10 = *reinterpret_cast<const float4*>(fb + (y0 * W + x1) * C);
    float4 r01 = *reinterpret_cast<const float4*>(fb + (y1 * W + x0) * C);
    float4 r11 = *reinterpret_cast<const float4*>(fb + (y1 * W + x1) * C);
    auto mix = [&](const float4& raw, float wgt) {
        const __half2* hc = reinterpret_cast<const __half2*>(&raw);
#pragma unroll
        for (int c = 0; c < 4; ++c) {
            float2 f = __half22float2(hc[c]);
            acc[2 * c]     += wgt * f.x;
            acc[2 * c + 1] += wgt * f.y;
        }
    };
    mix(r00, g.w00); mix(r10, g.w10); mix(r01, g.w01); mix(r11, g.w11);
}

// ---------------------------------------------------------------------------
// Main kernel: oct-t LDS-gather pscan, k split into P parity classes.
// R7's PROVEN loop shape (double-buffered global_load_lds staging, one
// barrier per k, 73.7 KB LDS -> 2 blocks/CU so co-resident blocks hide each
// other's barrier drains), with staging volume cut 3x by sharing each frame
// across 8 t's: t-set(g) = {g, 11-g, 12+g, 23-g, 24+g, 35-g, 36+g, 47-g}.
// Block = (chunk, g, {par, b}); k = par, par+P, ..., <= 47-g.
// grid = (9, 6, 2P) = 432 blocks at P=4.
// par==0 writes `out`; par p>0 writes part + (p-1)*OUT_ELEMS; reduce sums.
// ---------------------------------------------------------------------------
template <int P>
__global__ __launch_bounds__(256) void scan_oct_kernel(const float* __restrict__ cum2,
                                                       const __half* __restrict__ imgH,
                                                       float* __restrict__ out,
                                                       float* __restrict__ part) {
    const int tid  = threadIdx.x;
    const int pix0 = blockIdx.x * TPB;
    const int pix  = pix0 + tid;
    const int g    = blockIdx.y;
    const int par  = blockIdx.z % P;
    const int b    = blockIdx.z / P;

    int tj[8];
#pragma unroll
    for (int j = 0; j < 4; ++j) {
        tj[2 * j]     = 12 * j + g;
        tj[2 * j + 1] = 12 * j + 11 - g;
    }
    const int kmax = 47 - g;

    const int w = pix % W;
    const int h = pix / W;
    const float base_gx_p1 = (2 * w + 1) * (1.0f / W);
    const float base_gy    = (2 * h + 1) * (1.0f / H) - 1.0f;

    const float* cb = cum2 + ((size_t)b * L * HW + pix) * 2;
    float ctx[8], cty[8];
#pragma unroll
    for (int j = 0; j < 8; ++j) {
        float2 c = *reinterpret_cast<const float2*>(cb + (size_t)tj[j] * HW * 2);
        ctx[j] = c.x; cty[j] = c.y;
    }

    float acc[8][C];
#pragma unroll
    for (int j = 0; j < 8; ++j)
#pragma unroll
        for (int c = 0; c < C; ++c) acc[j][c] = 0.0f;

    // 73.7 KB: two fp16 frame buffers (epilogue reuses as fp32 [64][256])
    __shared__ __align__(16) unsigned char smem[2 * HW * C * 2];
    __half* fr0 = reinterpret_cast<__half*>(smem);
    __half* fr1 = reinterpret_cast<__half*>(smem + HW * C * 2);

    const __half* gb = imgH + (size_t)b * L * HW * C;

    stage_frame(gb + (size_t)par * HW * C, fr0, tid);       // frame k=par
    float2 ck = *reinterpret_cast<const float2*>(cb + (size_t)par * HW * 2);
    __syncthreads();                                        // staging visible

    int cur = 0;
    for (int k = par; k <= kmax; k += P) {
        __half* nb = cur ? fr0 : fr1;
        const __half* fb = cur ? fr1 : fr0;
        if (k + P <= kmax)
            stage_frame(gb + (size_t)(k + P) * HW * C, nb, tid);
        float2 ckn = ck;
        if (k + P <= kmax)
            ckn = *reinterpret_cast<const float2*>(cb + (size_t)(k + P) * HW * 2);

#pragma unroll
        for (int j = 0; j < 8; ++j) {
            if (tj[j] >= k) {   // block-uniform guard
                SampleGeom gm = sample_geom(base_gx_p1, base_gy,
                                            ctx[j] - ck.x, cty[j] - ck.y);
                gather_mix(fb, gm, acc[j]);
            }
        }

        ck = ckn;
        __syncthreads();    // gathers done + next staging landed -> safe swap
        cur ^= 1;
    }

    // ---- epilogue: transpose acc through LDS for coalesced stores ----
    float* accT = reinterpret_cast<float*>(smem);       // [64][256] = 64 KB
#pragma unroll
    for (int j = 0; j < 8; ++j)
#pragma unroll
        for (int c = 0; c < C; ++c)
            accT[(j * 8 + c) * TPB + tid] = acc[j][c];
    __syncthreads();

    float* dst = (par == 0) ? out : (part + (size_t)(par - 1) * OUT_ELEMS);
    const int lane = tid & 63;
    const int wv   = tid >> 6;
#pragma unroll
    for (int r = 0; r < 16; ++r) {
        int pl = wv + 4 * r;            // plane 0..63 = (j, c)
        int j  = pl >> 3, c = pl & 7;
        float4 v = *reinterpret_cast<float4*>(&accT[pl * TPB + lane * 4]);
        *reinterpret_cast<float4*>(dst + ((size_t)(b * L + tj[j]) * C + c) * HW
                                   + pix0 + lane * 4) = v;
    }
}

// ---------------------------------------------------------------------------
// Reduce: out += sum of (P-1) partials, fixed order -> deterministic.
// ---------------------------------------------------------------------------
template <int P>
__global__ void reduce_kernel(float* __restrict__ out, const float* __restrict__ part) {
    int i = blockIdx.x * blockDim.x + threadIdx.x;
    constexpr int N4 = OUT_ELEMS / 4;
    if (i < N4) {
        float4 a = reinterpret_cast<float4*>(out)[i];
#pragma unroll
        for (int p = 0; p < P - 1; ++p) {
            float4 q = reinterpret_cast<const float4*>(part + (size_t)p * OUT_ELEMS)[i];
            a.x += q.x; a.y += q.y; a.z += q.z; a.w += q.w;
        }
        reinterpret_cast<float4*>(out)[i] = a;
    }
}

// ---------------------------------------------------------------------------
extern "C" void kernel_launch(void* const* d_in, const int* in_sizes, int n_in,
                              void* d_out, int out_size, void* d_ws, size_t ws_size,
                              hipStream_t stream) {
    const float* flows  = (const float*)d_in[0];   // (B, L, 2, H, W) fp32
    const float* images = (const float*)d_in[1];   // (B, L, C, H, W) fp32
    float* out = (float*)d_out;                    // (B, L, C, H, W) fp32

    const size_t cum_elems  = (size_t)B * L * 2 * HW;     // 442,368 f32 (1.77 MB)
    const size_t imgH_elems = (size_t)B * L * HW * C;     // fp16 (7.08 MB)

    float*  cum2 = (float*)d_ws;
    __half* imgH = (__half*)(cum2 + cum_elems);
    float*  part = (float*)(imgH + imgH_elems);           // (P-1) x 7.08 MB partials

    const size_t base_bytes = cum_elems * 4 + imgH_elems * 2;   // 8.85 MB
    const size_t out_bytes  = (size_t)OUT_ELEMS * 4;            // 7.08 MB

    prep_kernel<<<CUM_BLOCKS + CONV_BLOCKS, 256, 0, stream>>>(flows, images, cum2, imgH);

    constexpr int N4 = OUT_ELEMS / 4;
    const int rblocks = (N4 + 255) / 256;

    if (ws_size >= base_bytes + 3 * out_bytes) {            // 30.1 MB
        dim3 grid(CHUNKS, NOCT, 2 * 4);                     // 432 blocks
        scan_oct_kernel<4><<<grid, 256, 0, stream>>>(cum2, imgH, out, part);
        reduce_kernel<4><<<rblocks, 256, 0, stream>>>(out, part);
    } else if (ws_size >= base_bytes + 2 * out_bytes) {     // 23.0 MB
        dim3 grid(CHUNKS, NOCT, 2 * 3);                     // 324 blocks
        scan_oct_kernel<3><<<grid, 256, 0, stream>>>(cum2, imgH, out, part);
        reduce_kernel<3><<<rblocks, 256, 0, stream>>>(out, part);
    } else {                                                // 15.9 MB (proven)
        dim3 grid(CHUNKS, NOCT, 2 * 2);                     // 216 blocks
        scan_oct_kernel<2><<<grid, 256, 0, stream>>>(cum2, imgH, out, part);
        reduce_kernel<2><<<rblocks, 256, 0, stream>>>(out, part);
    }
}